// Round 14
// baseline (291.311 us; speedup 1.0000x reference)
//
#include <hip/hip_runtime.h>
#include <hip/hip_bf16.h>
#include <math.h>

typedef unsigned short ushort_t;
typedef short bf16x8 __attribute__((ext_vector_type(8)));
typedef float f32x4 __attribute__((ext_vector_type(4)));
typedef float f32x16 __attribute__((ext_vector_type(16)));

#define NH 16
#define DH 128
#define DM 2048
#define TSEQ 2048
#define BT 4096   // B*T

__device__ __forceinline__ void async16(const void* g, void* l) {
  __builtin_amdgcn_global_load_lds(
      (const __attribute__((address_space(1))) void*)g,
      (__attribute__((address_space(3))) void*)l, 16, 0, 0);
}

__device__ __forceinline__ f32x4 mfma16(bf16x8 a, bf16x8 b, f32x4 c) {
  return __builtin_amdgcn_mfma_f32_16x16x32_bf16(a, b, c, 0, 0, 0);
}
__device__ __forceinline__ f32x16 mfma32(bf16x8 a, bf16x8 b, f32x16 c) {
  return __builtin_amdgcn_mfma_f32_32x32x16_bf16(a, b, c, 0, 0, 0);
}

__device__ __forceinline__ ushort_t f2bf(float f) {
  __hip_bfloat16 h = __float2bfloat16(f);
  return *reinterpret_cast<ushort_t*>(&h);
}
__device__ __forceinline__ unsigned cvtpk_bf16(float lo, float hi_) {
  unsigned r;
  asm("v_cvt_pk_bf16_f32 %0, %1, %2" : "=v"(r) : "v"(lo), "v"(hi_));
  return r;
}
__device__ __forceinline__ float fexp2(float x) {
  float r; asm("v_exp_f32 %0, %1" : "=v"(r) : "v"(x)); return r;
}

#define VM0()  asm volatile("s_waitcnt vmcnt(0)" ::: "memory")
#define BARR() { asm volatile("" ::: "memory"); __builtin_amdgcn_s_barrier(); \
                 asm volatile("" ::: "memory"); }

// ---------------- fused fp32 -> bf16 conversion (x + 4 weights, one launch) ----------------
__global__ void cvt_all_kernel(const float* __restrict__ x,
                               const float* __restrict__ Wq, const float* __restrict__ Wk,
                               const float* __restrict__ Wv, const float* __restrict__ Wo,
                               ushort_t* __restrict__ xb,
                               ushort_t* __restrict__ Wqb, ushort_t* __restrict__ Wkb,
                               ushort_t* __restrict__ Wvb, ushort_t* __restrict__ Wob)
{
  const int i = blockIdx.x * blockDim.x + threadIdx.x;   // 0 .. 6M-1 float4 quads
  const float* src; ushort_t* dst; int off;
  if (i < (1 << 21)) {                    // x: 8M elems = 2M quads
    src = x; dst = xb; off = i;
  } else {
    const int j = i - (1 << 21);          // weights: 4M elems = 1M quads each
    const int w = j >> 20;
    off = j & ((1 << 20) - 1);
    src = (w == 0) ? Wq : (w == 1) ? Wk : (w == 2) ? Wv : Wo;
    dst = (w == 0) ? Wqb : (w == 1) ? Wkb : (w == 2) ? Wvb : Wob;
  }
  const float4 v = reinterpret_cast<const float4*>(src)[off];
  ushort4 u;
  u.x = f2bf(v.x); u.y = f2bf(v.y); u.z = f2bf(v.z); u.w = f2bf(v.w);
  reinterpret_cast<ushort4*>(dst)[off] = u;
}

// ---------------- fused QKV GEMM, single-barrier T3-minimum schedule ----------------
__device__ __forceinline__ void stage_half_g(const ushort_t* __restrict__ src,
                                             int row0, int k0,
                                             ushort_t* dst, int tid) {
#pragma unroll
  for (int i = 0; i < 2; ++i) {
    const int idx = i * 512 + tid;
    const int r = idx >> 3, ch = idx & 7;
    const int c = (ch ^ (r & 7)) * 8;           // pre-swizzled source chunk
    async16(src + (size_t)(row0 + r) * DM + k0 + c, dst + idx * 8);
  }
}

__global__ __launch_bounds__(512, 2)
void gemm_qkv_fused(const ushort_t* __restrict__ A,
                    const ushort_t* __restrict__ W_0, const ushort_t* __restrict__ W_1,
                    const ushort_t* __restrict__ W_2,
                    const float* __restrict__ b_0, const float* __restrict__ b_1,
                    const float* __restrict__ b_2,
                    ushort_t* __restrict__ outQ, ushort_t* __restrict__ outK,
                    ushort_t* __restrict__ outVt)
{
  constexpr int NK = DM / 64;
  __shared__ __attribute__((aligned(16))) ushort_t As[2][128 * 64];
  __shared__ __attribute__((aligned(16))) ushort_t Bs[2][3][128 * 64];

  const int n0 = blockIdx.x * 128;
  const int m0 = blockIdx.y * 128;
  const int tid = threadIdx.x;
  const int w = tid >> 6, l = tid & 63;
  const int wr = w >> 2, wc = w & 3;
  const int l15 = l & 15, l4 = l >> 4;

  f32x4 acc[3][4][2] = {};   // [z][mf][nf]
  bf16x8 afr[4][2], bfr[2][2];

  stage_half_g(A,   m0, 0, As[0],    tid);
  stage_half_g(W_0, n0, 0, Bs[0][0], tid);
  stage_half_g(W_1, n0, 0, Bs[0][1], tid);
  stage_half_g(W_2, n0, 0, Bs[0][2], tid);
  VM0();
  BARR();

  for (int kt = 0; kt < NK; ++kt) {
    const int cur = kt & 1;
    const bool more = (kt + 1 < NK);
    if (more) {
      const int k1 = (kt + 1) * 64;
      stage_half_g(A,   m0, k1, As[cur ^ 1],    tid);
      stage_half_g(W_0, n0, k1, Bs[cur ^ 1][0], tid);
      stage_half_g(W_1, n0, k1, Bs[cur ^ 1][1], tid);
      stage_half_g(W_2, n0, k1, Bs[cur ^ 1][2], tid);
    }

    {
      const char* p_ = reinterpret_cast<const char*>(As[cur]);
#pragma unroll
      for (int mf = 0; mf < 4; ++mf) {
        const int row_ = wr * 64 + mf * 16 + l15;
#pragma unroll
        for (int ks = 0; ks < 2; ++ks)
          afr[mf][ks] = *reinterpret_cast<const bf16x8*>(
              p_ + row_ * 128 + ((l4 * 16 + ks * 64) ^ ((row_ & 7) << 4)));
      }
    }
#pragma unroll
    for (int z = 0; z < 3; ++z) {
      const char* p_ = reinterpret_cast<const char*>(Bs[cur][z]);
#pragma unroll
      for (int nf = 0; nf < 2; ++nf) {
        const int row_ = wc * 32 + nf * 16 + l15;
#pragma unroll
        for (int ks = 0; ks < 2; ++ks)
          bfr[nf][ks] = *reinterpret_cast<const bf16x8*>(
              p_ + row_ * 128 + ((l4 * 16 + ks * 64) ^ ((row_ & 7) << 4)));
      }
      __builtin_amdgcn_s_setprio(1);
#pragma unroll
      for (int mf = 0; mf < 4; ++mf)
#pragma unroll
        for (int nf = 0; nf < 2; ++nf)
#pragma unroll
          for (int ks = 0; ks < 2; ++ks)
            acc[z][mf][nf] = mfma16(afr[mf][ks], bfr[nf][ks], acc[z][mf][nf]);
      __builtin_amdgcn_s_setprio(0);
    }

    if (more) { VM0(); }
    BARR();
  }

#pragma unroll
  for (int z = 0; z < 3; ++z) {
    const float* bias = (z == 0) ? b_0 : (z == 1) ? b_1 : b_2;
#pragma unroll
    for (int nf = 0; nf < 2; ++nf) {
      const int n = n0 + wc * 32 + nf * 16 + l15;
      const float bv = bias[n];
      const int hh = n >> 7, d = n & 127;
#pragma unroll
      for (int mf = 0; mf < 4; ++mf) {
#pragma unroll
        for (int r = 0; r < 4; ++r) {
          const int m = m0 + wr * 64 + mf * 16 + l4 * 4 + r;
          const float v = acc[z][mf][nf][r] + bv;
          const int b = m >> 11, t = m & 2047;
          const ushort_t val = f2bf(v);
          if (z == 2) {
            outVt[((size_t)(b * NH + hh) * DH + d) * TSEQ + t] = val;   // V transposed
          } else {
            ushort_t* dst = (z == 0) ? outQ : outK;
            dst[((size_t)(b * NH + hh) * TSEQ + t) * DH + d] = val;
          }
        }
      }
    }
  }
}

// ---------------- out-projection GEMM, single-barrier schedule ----------------
__device__ __forceinline__ void stage_ab(const ushort_t* __restrict__ A,
                                         const ushort_t* __restrict__ Wp,
                                         int m0, int n0, int k0,
                                         ushort_t* AsB, ushort_t* BsB,
                                         int w, int l)
{
#pragma unroll
  for (int i = 0; i < 4; ++i) {
    const int rb = (i * 4 + w) * 8;
    const int r = rb + (l >> 3);
    const int c = ((l & 7) * 8) ^ ((r & 7) * 8);   // pre-swizzled source col
    async16(A  + (size_t)(m0 + r) * DM + k0 + c, AsB + rb * 64);
    async16(Wp + (size_t)(n0 + r) * DM + k0 + c, BsB + rb * 64);
  }
}

__global__ __launch_bounds__(256)
void gemm_proj_kernel(const ushort_t* __restrict__ A, const ushort_t* __restrict__ W_0,
                      const float* __restrict__ b_0, float* __restrict__ outF)
{
  constexpr int NK = DM / 64;
  __shared__ __attribute__((aligned(16))) ushort_t As[2][128 * 64];
  __shared__ __attribute__((aligned(16))) ushort_t Bs[2][128 * 64];

  const int n0 = blockIdx.x * 128;
  const int m0 = blockIdx.y * 128;
  const int tid = threadIdx.x;
  const int w = tid >> 6, l = tid & 63;
  const int wm = w >> 1, wn = w & 1;
  const int l15 = l & 15, l4 = l >> 4;

  f32x4 zero = {0.f, 0.f, 0.f, 0.f};
  f32x4 acc[4][4];
#pragma unroll
  for (int i = 0; i < 4; ++i)
#pragma unroll
    for (int j = 0; j < 4; ++j) acc[i][j] = zero;

  stage_ab(A, W_0, m0, n0, 0, As[0], Bs[0], w, l);
  VM0();
  BARR();

  for (int kt = 0; kt < NK; ++kt) {
    const int cur = kt & 1;
    const bool more = (kt + 1 < NK);
    if (more)
      stage_ab(A, W_0, m0, n0, (kt + 1) * 64, As[cur ^ 1], Bs[cur ^ 1], w, l);

#pragma unroll
    for (int ks = 0; ks < 2; ++ks) {
      bf16x8 af[4], bfr[4];
#pragma unroll
      for (int mf = 0; mf < 4; ++mf) {
        const int row = wm * 64 + mf * 16 + l15;
        const int byte_ = row * 128 + ((l4 * 16 + ks * 64) ^ ((row & 7) << 4));
        af[mf] = *reinterpret_cast<const bf16x8*>(reinterpret_cast<const char*>(As[cur]) + byte_);
      }
#pragma unroll
      for (int nf = 0; nf < 4; ++nf) {
        const int row = wn * 64 + nf * 16 + l15;
        const int byte_ = row * 128 + ((l4 * 16 + ks * 64) ^ ((row & 7) << 4));
        bfr[nf] = *reinterpret_cast<const bf16x8*>(reinterpret_cast<const char*>(Bs[cur]) + byte_);
      }
      __builtin_amdgcn_s_setprio(1);
#pragma unroll
      for (int mf = 0; mf < 4; ++mf)
#pragma unroll
        for (int nf = 0; nf < 4; ++nf)
          acc[mf][nf] = mfma16(af[mf], bfr[nf], acc[mf][nf]);
      __builtin_amdgcn_s_setprio(0);
    }

    if (more) { VM0(); }
    BARR();
  }

#pragma unroll
  for (int nf = 0; nf < 4; ++nf) {
    const int n = n0 + wn * 64 + nf * 16 + l15;
    const float bv = b_0[n];
#pragma unroll
    for (int mf = 0; mf < 4; ++mf) {
#pragma unroll
      for (int r = 0; r < 4; ++r) {
        const int m = m0 + wm * 64 + mf * 16 + l4 * 4 + r;
        outF[(size_t)m * DM + n] = acc[mf][nf][r] + bv;
      }
    }
  }
}

// ---------------- causal flash attention ----------------
// EQUAL-qt CU pairing (kept from R13): slots s and s+32 within an XCD get the
// SAME qt on different heads, so the critical 32-iter blocks run 2 blocks/CU
// (2 waves/SIMD TLP) the whole way. Cross-half reductions use the proven
// __shfl_xor (R13's permlane asm was miscompiled: tied "+v" operands with
// identical init collapse to ONE phys register -> v clobbered).
__device__ __forceinline__ void stage_kv(const ushort_t* __restrict__ Kg,
                                         const ushort_t* __restrict__ Vt,
                                         size_t kbase, size_t vbase, int kv0,
                                         ushort_t* KsB, ushort_t* VsB, int tid)
{
#pragma unroll
  for (int i = 0; i < 4; ++i) {           // K tile [64 kv][128 d], 16KB
    const int idx = i * 256 + tid;
    const int r = idx >> 4, ch = idx & 15;
    const int c = (ch ^ (r & 7)) * 8;
    async16(Kg + kbase + (size_t)(kv0 + r) * DH + c, KsB + idx * 8);
  }
#pragma unroll
  for (int i = 0; i < 4; ++i) {           // V^T tile [128 d][64 kv], 16KB
    const int idx = i * 256 + tid;
    const int d = idx >> 3, ch = idx & 7;
    const int c = (ch ^ (d & 7)) * 8;
    async16(Vt + vbase + (size_t)d * TSEQ + kv0 + c, VsB + idx * 8);
  }
}

__global__ __launch_bounds__(256)
void attn_kernel(const ushort_t* __restrict__ Q, const ushort_t* __restrict__ Kg,
                 const ushort_t* __restrict__ Vt, ushort_t* __restrict__ ctx)
{
  __shared__ __attribute__((aligned(16))) ushort_t Ks[2][64 * 128];
  __shared__ __attribute__((aligned(16))) ushort_t Vs[2][128 * 64];

  const int fid = (int)blockIdx.x + 16 * (int)blockIdx.y;
  const int xcd = fid & 7;
  const int s   = fid >> 3;                       // 0..63 within XCD
  // equal-qt pairing: qt(s) == qt(s+32); bh-local = bit0(s) | bit5(s)<<1
  const int qt  = (s & 31) >> 1;
  const int bh  = xcd * 4 + ((s & 1) | ((s >> 5) << 1));

  const int tid = threadIdx.x, w = tid >> 6, l = tid & 63;
  const int l31 = l & 31, hi = l >> 5;
  const size_t kbase = (size_t)bh * TSEQ * DH;
  const size_t vbase = (size_t)bh * DH * TSEQ;
  const int bq0 = qt * 128;
  const int wq0 = bq0 + w * 32;
  const int NT = qt * 2 + 2;
  const int q = wq0 + l31;
  const float C2 = 0.12753842f;           // log2(e)/sqrt(128)
  const float NEG = -3.0e38f;

  bf16x8 aq[8];
  {
    const ushort_t* qp = Q + kbase + (size_t)q * DH + hi * 8;
#pragma unroll
    for (int st = 0; st < 8; ++st)
      aq[st] = *reinterpret_cast<const bf16x8*>(qp + st * 16);
  }

  f32x16 o[4] = {};
  float m_r = NEG, l_r = 0.f;

  stage_kv(Kg, Vt, kbase, vbase, 0, Ks[0], Vs[0], tid);
  VM0();
  BARR();

  for (int kt = 0; kt < NT; ++kt) {
    const int kv0 = kt * 64, cur = kt & 1;
    const bool more = (kt + 1 < NT);
    if (more)
      stage_kv(Kg, Vt, kbase, vbase, kv0 + 64, Ks[cur ^ 1], Vs[cur ^ 1], tid);

    if (kv0 <= wq0 + 31) {
      const char* ksb = reinterpret_cast<const char*>(Ks[cur]);
      f32x16 s0 = {}, s1 = {};
      __builtin_amdgcn_s_setprio(1);
#pragma unroll
      for (int st = 0; st < 8; ++st) {
        const int byt = l31 * 256 + ((hi * 16 + st * 32) ^ ((l31 & 7) << 4));
        bf16x8 ak0 = *reinterpret_cast<const bf16x8*>(ksb + byt);
        bf16x8 ak1 = *reinterpret_cast<const bf16x8*>(ksb + byt + 8192);
        s0 = mfma32(ak0, aq[st], s0);
        s1 = mfma32(ak1, aq[st], s1);
      }
      __builtin_amdgcn_s_setprio(0);

      if (kv0 + 63 > wq0) {
#pragma unroll
        for (int r = 0; r < 16; ++r) {
          const int kvl = kv0 + (r & 3) + 8 * (r >> 2) + 4 * hi;
          if (kvl > q)      s0[r] = NEG;
          if (kvl + 32 > q) s1[r] = NEG;
        }
      }

      float t8[8];
#pragma unroll
      for (int r = 0; r < 8; ++r)
        t8[r] = fmaxf(fmaxf(s0[r], s0[r + 8]), fmaxf(s1[r], s1[r + 8]));
#pragma unroll
      for (int r = 0; r < 4; ++r) t8[r] = fmaxf(t8[r], t8[r + 4]);
      float mt = fmaxf(fmaxf(t8[0], t8[1]), fmaxf(t8[2], t8[3]));
      mt = fmaxf(mt, __shfl_xor(mt, 32));

      const float mnew = fmaxf(m_r, mt);
      if (!__all(mt <= m_r + 16.0f)) {
        const float alpha = fexp2((m_r - mnew) * C2);
        l_r *= alpha;
#pragma unroll
        for (int d0 = 0; d0 < 4; ++d0) o[d0] *= alpha;
        m_r = mnew;
      }

#pragma unroll
      for (int r = 0; r < 16; ++r) {
        s0[r] = fexp2((s0[r] - m_r) * C2);
        s1[r] = fexp2((s1[r] - m_r) * C2);
      }
      float sm[8];
#pragma unroll
      for (int r = 0; r < 8; ++r) sm[r] = (s0[r] + s0[r + 8]) + (s1[r] + s1[r + 8]);
#pragma unroll
      for (int r = 0; r < 4; ++r) sm[r] += sm[r + 4];
      float ls = (sm[0] + sm[1]) + (sm[2] + sm[3]);
      ls += __shfl_xor(ls, 32);
      l_r += ls;

      const char* vsb = reinterpret_cast<const char*>(Vs[cur]);
#pragma unroll
      for (int ks = 0; ks < 4; ++ks) {
        float pj[8];
#pragma unroll
        for (int j = 0; j < 8; ++j)
          pj[j] = (ks >> 1) ? s1[(ks & 1) * 8 + j] : s0[(ks & 1) * 8 + j];
        unsigned cA = cvtpk_bf16(pj[0], pj[1]);
        unsigned cB = cvtpk_bf16(pj[2], pj[3]);
        unsigned cC = cvtpk_bf16(pj[4], pj[5]);
        unsigned cD = cvtpk_bf16(pj[6], pj[7]);
        asm volatile("v_permlane32_swap_b32 %0, %1" : "+v"(cA), "+v"(cC));
        asm volatile("v_permlane32_swap_b32 %0, %1" : "+v"(cB), "+v"(cD));
        union { unsigned u[4]; bf16x8 v; } pa;
        pa.u[0] = cA; pa.u[1] = cB; pa.u[2] = cC; pa.u[3] = cD;
        __builtin_amdgcn_s_setprio(1);
#pragma unroll
        for (int d0 = 0; d0 < 4; ++d0) {
          const int byt = (d0 * 32 + l31) * 128 + ((ks * 32 + hi * 16) ^ ((l31 & 7) << 4));
          bf16x8 av = *reinterpret_cast<const bf16x8*>(vsb + byt);
          o[d0] = mfma32(av, pa.v, o[d0]);
        }
        __builtin_amdgcn_s_setprio(0);
      }
    }

    if (more) { VM0(); }
    BARR();
  }

  const size_t obase = (size_t)(bh >> 4) * TSEQ * DM + (size_t)(bh & 15) * DH;
  const float inv = 1.0f / l_r;
  ushort_t* cp = ctx + obase + (size_t)q * DM + hi * 4;
#pragma unroll
  for (int d0 = 0; d0 < 4; ++d0) {
#pragma unroll
    for (int g = 0; g < 4; ++g) {
      ushort4 u;
      u.x = f2bf(o[d0][4 * g + 0] * inv);
      u.y = f2bf(o[d0][4 * g + 1] * inv);
      u.z = f2bf(o[d0][4 * g + 2] * inv);
      u.w = f2bf(o[d0][4 * g + 3] * inv);
      *reinterpret_cast<ushort4*>(cp + d0 * 32 + 8 * g) = u;
    }
  }
}

extern "C" void kernel_launch(void* const* d_in, const int* in_sizes, int n_in,
                              void* d_out, int out_size, void* d_ws, size_t ws_size,
                              hipStream_t stream) {
  const float* x  = (const float*)d_in[0];
  const float* Wq = (const float*)d_in[1];
  const float* bq = (const float*)d_in[2];
  const float* Wk = (const float*)d_in[3];
  const float* bk = (const float*)d_in[4];
  const float* Wv = (const float*)d_in[5];
  const float* bv = (const float*)d_in[6];
  const float* Wo = (const float*)d_in[7];
  const float* bo = (const float*)d_in[8];
  float* out = (float*)d_out;

  char* ws = (char*)d_ws;
  ushort_t* xb  = (ushort_t*)ws;  ws += (size_t)BT * DM * 2;      // x bf16; reused as ctx
  ushort_t* Wqb = (ushort_t*)ws;  ws += (size_t)DM * DM * 2;
  ushort_t* Wkb = (ushort_t*)ws;  ws += (size_t)DM * DM * 2;
  ushort_t* Wvb = (ushort_t*)ws;  ws += (size_t)DM * DM * 2;
  ushort_t* Wob = (ushort_t*)ws;  ws += (size_t)DM * DM * 2;
  ushort_t* Qb  = (ushort_t*)ws;  ws += (size_t)BT * DM * 2;
  ushort_t* Kb  = (ushort_t*)ws;  ws += (size_t)BT * DM * 2;
  ushort_t* Vtb = (ushort_t*)ws;  ws += (size_t)BT * DM * 2;
  ushort_t* ctxb = xb;   // alias: x dead after QKV GEMM

  // fused conversion: 6M float4 quads total (x 2M + 4 weights x 1M)
  cvt_all_kernel<<<6 * (1 << 20) / 256, 256, 0, stream>>>(
      x, Wq, Wk, Wv, Wo, xb, Wqb, Wkb, Wvb, Wob);

  gemm_qkv_fused<<<dim3(16, 32), 512, 0, stream>>>(
      xb, Wqb, Wkb, Wvb, bq, bk, bv, Qb, Kb, Vtb);

  attn_kernel<<<dim3(TSEQ / 128, 32), 256, 0, stream>>>(Qb, Kb, Vtb, ctxb);

  gemm_proj_kernel<<<dim3(16, 32), 256, 0, stream>>>(ctxb, Wob, bo, out);
}

// Round 16
// 271.288 us; speedup vs baseline: 1.0738x; 1.0738x over previous
//
#include <hip/hip_runtime.h>
#include <hip/hip_bf16.h>
#include <math.h>

typedef unsigned short ushort_t;
typedef short bf16x8 __attribute__((ext_vector_type(8)));
typedef float f32x4 __attribute__((ext_vector_type(4)));
typedef float f32x16 __attribute__((ext_vector_type(16)));

#define NH 16
#define DH 128
#define DM 2048
#define TSEQ 2048
#define BT 4096   // B*T

__device__ __forceinline__ void async16(const void* g, void* l) {
  __builtin_amdgcn_global_load_lds(
      (const __attribute__((address_space(1))) void*)g,
      (__attribute__((address_space(3))) void*)l, 16, 0, 0);
}

__device__ __forceinline__ f32x4 mfma16(bf16x8 a, bf16x8 b, f32x4 c) {
  return __builtin_amdgcn_mfma_f32_16x16x32_bf16(a, b, c, 0, 0, 0);
}
__device__ __forceinline__ f32x16 mfma32(bf16x8 a, bf16x8 b, f32x16 c) {
  return __builtin_amdgcn_mfma_f32_32x32x16_bf16(a, b, c, 0, 0, 0);
}

__device__ __forceinline__ ushort_t f2bf(float f) {
  __hip_bfloat16 h = __float2bfloat16(f);
  return *reinterpret_cast<ushort_t*>(&h);
}
__device__ __forceinline__ unsigned cvtpk_bf16(float lo, float hi_) {
  unsigned r;
  asm("v_cvt_pk_bf16_f32 %0, %1, %2" : "=v"(r) : "v"(lo), "v"(hi_));
  return r;
}
__device__ __forceinline__ float fexp2(float x) {
  float r; asm("v_exp_f32 %0, %1" : "=v"(r) : "v"(x)); return r;
}

#define VM0()  asm volatile("s_waitcnt vmcnt(0)" ::: "memory")
#define BARR() { asm volatile("" ::: "memory"); __builtin_amdgcn_s_barrier(); \
                 asm volatile("" ::: "memory"); }

// ---------------- fused fp32 -> bf16 conversion (x + 4 weights, one launch) ----------------
__global__ void cvt_all_kernel(const float* __restrict__ x,
                               const float* __restrict__ Wq, const float* __restrict__ Wk,
                               const float* __restrict__ Wv, const float* __restrict__ Wo,
                               ushort_t* __restrict__ xb,
                               ushort_t* __restrict__ Wqb, ushort_t* __restrict__ Wkb,
                               ushort_t* __restrict__ Wvb, ushort_t* __restrict__ Wob)
{
  const int i = blockIdx.x * blockDim.x + threadIdx.x;   // 0 .. 6M-1 float4 quads
  const float* src; ushort_t* dst; int off;
  if (i < (1 << 21)) {                    // x: 8M elems = 2M quads
    src = x; dst = xb; off = i;
  } else {
    const int j = i - (1 << 21);          // weights: 4M elems = 1M quads each
    const int w = j >> 20;
    off = j & ((1 << 20) - 1);
    src = (w == 0) ? Wq : (w == 1) ? Wk : (w == 2) ? Wv : Wo;
    dst = (w == 0) ? Wqb : (w == 1) ? Wkb : (w == 2) ? Wvb : Wob;
  }
  const float4 v = reinterpret_cast<const float4*>(src)[off];
  ushort4 u;
  u.x = f2bf(v.x); u.y = f2bf(v.y); u.z = f2bf(v.z); u.w = f2bf(v.w);
  reinterpret_cast<ushort4*>(dst)[off] = u;
}

// ---------------- fused QKV GEMM, single-barrier T3-minimum schedule ----------------
__device__ __forceinline__ void stage_half_g(const ushort_t* __restrict__ src,
                                             int row0, int k0,
                                             ushort_t* dst, int tid) {
#pragma unroll
  for (int i = 0; i < 2; ++i) {
    const int idx = i * 512 + tid;
    const int r = idx >> 3, ch = idx & 7;
    const int c = (ch ^ (r & 7)) * 8;           // pre-swizzled source chunk
    async16(src + (size_t)(row0 + r) * DM + k0 + c, dst + idx * 8);
  }
}

__global__ __launch_bounds__(512, 2)
void gemm_qkv_fused(const ushort_t* __restrict__ A,
                    const ushort_t* __restrict__ W_0, const ushort_t* __restrict__ W_1,
                    const ushort_t* __restrict__ W_2,
                    const float* __restrict__ b_0, const float* __restrict__ b_1,
                    const float* __restrict__ b_2,
                    ushort_t* __restrict__ outQ, ushort_t* __restrict__ outK,
                    ushort_t* __restrict__ outVt)
{
  constexpr int NK = DM / 64;
  __shared__ __attribute__((aligned(16))) ushort_t As[2][128 * 64];
  __shared__ __attribute__((aligned(16))) ushort_t Bs[2][3][128 * 64];

  const int n0 = blockIdx.x * 128;
  const int m0 = blockIdx.y * 128;
  const int tid = threadIdx.x;
  const int w = tid >> 6, l = tid & 63;
  const int wr = w >> 2, wc = w & 3;
  const int l15 = l & 15, l4 = l >> 4;

  f32x4 acc[3][4][2] = {};   // [z][mf][nf]
  bf16x8 afr[4][2], bfr[2][2];

  stage_half_g(A,   m0, 0, As[0],    tid);
  stage_half_g(W_0, n0, 0, Bs[0][0], tid);
  stage_half_g(W_1, n0, 0, Bs[0][1], tid);
  stage_half_g(W_2, n0, 0, Bs[0][2], tid);
  VM0();
  BARR();

  for (int kt = 0; kt < NK; ++kt) {
    const int cur = kt & 1;
    const bool more = (kt + 1 < NK);
    if (more) {
      const int k1 = (kt + 1) * 64;
      stage_half_g(A,   m0, k1, As[cur ^ 1],    tid);
      stage_half_g(W_0, n0, k1, Bs[cur ^ 1][0], tid);
      stage_half_g(W_1, n0, k1, Bs[cur ^ 1][1], tid);
      stage_half_g(W_2, n0, k1, Bs[cur ^ 1][2], tid);
    }

    {
      const char* p_ = reinterpret_cast<const char*>(As[cur]);
#pragma unroll
      for (int mf = 0; mf < 4; ++mf) {
        const int row_ = wr * 64 + mf * 16 + l15;
#pragma unroll
        for (int ks = 0; ks < 2; ++ks)
          afr[mf][ks] = *reinterpret_cast<const bf16x8*>(
              p_ + row_ * 128 + ((l4 * 16 + ks * 64) ^ ((row_ & 7) << 4)));
      }
    }
#pragma unroll
    for (int z = 0; z < 3; ++z) {
      const char* p_ = reinterpret_cast<const char*>(Bs[cur][z]);
#pragma unroll
      for (int nf = 0; nf < 2; ++nf) {
        const int row_ = wc * 32 + nf * 16 + l15;
#pragma unroll
        for (int ks = 0; ks < 2; ++ks)
          bfr[nf][ks] = *reinterpret_cast<const bf16x8*>(
              p_ + row_ * 128 + ((l4 * 16 + ks * 64) ^ ((row_ & 7) << 4)));
      }
      __builtin_amdgcn_s_setprio(1);
#pragma unroll
      for (int mf = 0; mf < 4; ++mf)
#pragma unroll
        for (int nf = 0; nf < 2; ++nf)
#pragma unroll
          for (int ks = 0; ks < 2; ++ks)
            acc[z][mf][nf] = mfma16(afr[mf][ks], bfr[nf][ks], acc[z][mf][nf]);
      __builtin_amdgcn_s_setprio(0);
    }

    if (more) { VM0(); }
    BARR();
  }

#pragma unroll
  for (int z = 0; z < 3; ++z) {
    const float* bias = (z == 0) ? b_0 : (z == 1) ? b_1 : b_2;
#pragma unroll
    for (int nf = 0; nf < 2; ++nf) {
      const int n = n0 + wc * 32 + nf * 16 + l15;
      const float bv = bias[n];
      const int hh = n >> 7, d = n & 127;
#pragma unroll
      for (int mf = 0; mf < 4; ++mf) {
#pragma unroll
        for (int r = 0; r < 4; ++r) {
          const int m = m0 + wr * 64 + mf * 16 + l4 * 4 + r;
          const float v = acc[z][mf][nf][r] + bv;
          const int b = m >> 11, t = m & 2047;
          const ushort_t val = f2bf(v);
          if (z == 2) {
            outVt[((size_t)(b * NH + hh) * DH + d) * TSEQ + t] = val;   // V transposed
          } else {
            ushort_t* dst = (z == 0) ? outQ : outK;
            dst[((size_t)(b * NH + hh) * TSEQ + t) * DH + d] = val;
          }
        }
      }
    }
  }
}

// ---------------- out-projection GEMM, single-barrier schedule ----------------
__device__ __forceinline__ void stage_ab(const ushort_t* __restrict__ A,
                                         const ushort_t* __restrict__ Wp,
                                         int m0, int n0, int k0,
                                         ushort_t* AsB, ushort_t* BsB,
                                         int w, int l)
{
#pragma unroll
  for (int i = 0; i < 4; ++i) {
    const int rb = (i * 4 + w) * 8;
    const int r = rb + (l >> 3);
    const int c = ((l & 7) * 8) ^ ((r & 7) * 8);   // pre-swizzled source col
    async16(A  + (size_t)(m0 + r) * DM + k0 + c, AsB + rb * 64);
    async16(Wp + (size_t)(n0 + r) * DM + k0 + c, BsB + rb * 64);
  }
}

__global__ __launch_bounds__(256)
void gemm_proj_kernel(const ushort_t* __restrict__ A, const ushort_t* __restrict__ W_0,
                      const float* __restrict__ b_0, float* __restrict__ outF)
{
  constexpr int NK = DM / 64;
  __shared__ __attribute__((aligned(16))) ushort_t As[2][128 * 64];
  __shared__ __attribute__((aligned(16))) ushort_t Bs[2][128 * 64];

  const int n0 = blockIdx.x * 128;
  const int m0 = blockIdx.y * 128;
  const int tid = threadIdx.x;
  const int w = tid >> 6, l = tid & 63;
  const int wm = w >> 1, wn = w & 1;
  const int l15 = l & 15, l4 = l >> 4;

  f32x4 zero = {0.f, 0.f, 0.f, 0.f};
  f32x4 acc[4][4];
#pragma unroll
  for (int i = 0; i < 4; ++i)
#pragma unroll
    for (int j = 0; j < 4; ++j) acc[i][j] = zero;

  stage_ab(A, W_0, m0, n0, 0, As[0], Bs[0], w, l);
  VM0();
  BARR();

  for (int kt = 0; kt < NK; ++kt) {
    const int cur = kt & 1;
    const bool more = (kt + 1 < NK);
    if (more)
      stage_ab(A, W_0, m0, n0, (kt + 1) * 64, As[cur ^ 1], Bs[cur ^ 1], w, l);

#pragma unroll
    for (int ks = 0; ks < 2; ++ks) {
      bf16x8 af[4], bfr[4];
#pragma unroll
      for (int mf = 0; mf < 4; ++mf) {
        const int row = wm * 64 + mf * 16 + l15;
        const int byte_ = row * 128 + ((l4 * 16 + ks * 64) ^ ((row & 7) << 4));
        af[mf] = *reinterpret_cast<const bf16x8*>(reinterpret_cast<const char*>(As[cur]) + byte_);
      }
#pragma unroll
      for (int nf = 0; nf < 4; ++nf) {
        const int row = wn * 64 + nf * 16 + l15;
        const int byte_ = row * 128 + ((l4 * 16 + ks * 64) ^ ((row & 7) << 4));
        bfr[nf] = *reinterpret_cast<const bf16x8*>(reinterpret_cast<const char*>(Bs[cur]) + byte_);
      }
      __builtin_amdgcn_s_setprio(1);
#pragma unroll
      for (int mf = 0; mf < 4; ++mf)
#pragma unroll
        for (int nf = 0; nf < 4; ++nf)
          acc[mf][nf] = mfma16(af[mf], bfr[nf], acc[mf][nf]);
      __builtin_amdgcn_s_setprio(0);
    }

    if (more) { VM0(); }
    BARR();
  }

#pragma unroll
  for (int nf = 0; nf < 4; ++nf) {
    const int n = n0 + wn * 64 + nf * 16 + l15;
    const float bv = b_0[n];
#pragma unroll
    for (int mf = 0; mf < 4; ++mf) {
#pragma unroll
      for (int r = 0; r < 4; ++r) {
        const int m = m0 + wm * 64 + mf * 16 + l4 * 4 + r;
        outF[(size_t)m * DM + n] = acc[mf][nf][r] + bv;
      }
    }
  }
}

// ---------------- causal flash attention (R12-proven exact state) ----------------
// Complementary qt pairing: slots s and s+32 on a CU get (qt, 15-qt) of the
// SAME bh -> every CU does exactly 36 iterations total and the pair shares KV
// lines. Cross-half reductions via __shfl_xor (the only validated form; both
// permlane-based xhalf variants failed deterministically, R13/R15).
__device__ __forceinline__ void stage_kv(const ushort_t* __restrict__ Kg,
                                         const ushort_t* __restrict__ Vt,
                                         size_t kbase, size_t vbase, int kv0,
                                         ushort_t* KsB, ushort_t* VsB, int tid)
{
#pragma unroll
  for (int i = 0; i < 4; ++i) {           // K tile [64 kv][128 d], 16KB
    const int idx = i * 256 + tid;
    const int r = idx >> 4, ch = idx & 15;
    const int c = (ch ^ (r & 7)) * 8;
    async16(Kg + kbase + (size_t)(kv0 + r) * DH + c, KsB + idx * 8);
  }
#pragma unroll
  for (int i = 0; i < 4; ++i) {           // V^T tile [128 d][64 kv], 16KB
    const int idx = i * 256 + tid;
    const int d = idx >> 3, ch = idx & 7;
    const int c = (ch ^ (d & 7)) * 8;
    async16(Vt + vbase + (size_t)d * TSEQ + kv0 + c, VsB + idx * 8);
  }
}

__global__ __launch_bounds__(256)
void attn_kernel(const ushort_t* __restrict__ Q, const ushort_t* __restrict__ Kg,
                 const ushort_t* __restrict__ Vt, ushort_t* __restrict__ ctx)
{
  __shared__ __attribute__((aligned(16))) ushort_t Ks[2][64 * 128];
  __shared__ __attribute__((aligned(16))) ushort_t Vs[2][128 * 64];

  const int fid = (int)blockIdx.x + 16 * (int)blockIdx.y;
  const int xcd = fid & 7;
  const int s   = fid >> 3;
  const int bh  = xcd * 4 + (s & 3);
  const int qt  = (s < 32) ? (15 - (s >> 2)) : ((s - 32) >> 2);

  const int tid = threadIdx.x, w = tid >> 6, l = tid & 63;
  const int l31 = l & 31, hi = l >> 5;
  const size_t kbase = (size_t)bh * TSEQ * DH;
  const size_t vbase = (size_t)bh * DH * TSEQ;
  const int bq0 = qt * 128;
  const int wq0 = bq0 + w * 32;
  const int NT = qt * 2 + 2;
  const int q = wq0 + l31;
  const float C2 = 0.12753842f;           // log2(e)/sqrt(128)
  const float NEG = -3.0e38f;

  bf16x8 aq[8];
  {
    const ushort_t* qp = Q + kbase + (size_t)q * DH + hi * 8;
#pragma unroll
    for (int st = 0; st < 8; ++st)
      aq[st] = *reinterpret_cast<const bf16x8*>(qp + st * 16);
  }

  f32x16 o[4] = {};
  float m_r = NEG, l_r = 0.f;

  stage_kv(Kg, Vt, kbase, vbase, 0, Ks[0], Vs[0], tid);
  VM0();
  BARR();

  for (int kt = 0; kt < NT; ++kt) {
    const int kv0 = kt * 64, cur = kt & 1;
    const bool more = (kt + 1 < NT);
    if (more)
      stage_kv(Kg, Vt, kbase, vbase, kv0 + 64, Ks[cur ^ 1], Vs[cur ^ 1], tid);

    if (kv0 <= wq0 + 31) {
      const char* ksb = reinterpret_cast<const char*>(Ks[cur]);
      f32x16 s0 = {}, s1 = {};
      __builtin_amdgcn_s_setprio(1);
#pragma unroll
      for (int st = 0; st < 8; ++st) {
        const int byt = l31 * 256 + ((hi * 16 + st * 32) ^ ((l31 & 7) << 4));
        bf16x8 ak0 = *reinterpret_cast<const bf16x8*>(ksb + byt);
        bf16x8 ak1 = *reinterpret_cast<const bf16x8*>(ksb + byt + 8192);
        s0 = mfma32(ak0, aq[st], s0);
        s1 = mfma32(ak1, aq[st], s1);
      }
      __builtin_amdgcn_s_setprio(0);

      if (kv0 + 63 > wq0) {
#pragma unroll
        for (int r = 0; r < 16; ++r) {
          const int kvl = kv0 + (r & 3) + 8 * (r >> 2) + 4 * hi;
          if (kvl > q)      s0[r] = NEG;
          if (kvl + 32 > q) s1[r] = NEG;
        }
      }

      float t8[8];
#pragma unroll
      for (int r = 0; r < 8; ++r)
        t8[r] = fmaxf(fmaxf(s0[r], s0[r + 8]), fmaxf(s1[r], s1[r + 8]));
#pragma unroll
      for (int r = 0; r < 4; ++r) t8[r] = fmaxf(t8[r], t8[r + 4]);
      float mt = fmaxf(fmaxf(t8[0], t8[1]), fmaxf(t8[2], t8[3]));
      mt = fmaxf(mt, __shfl_xor(mt, 32));

      const float mnew = fmaxf(m_r, mt);
      if (!__all(mt <= m_r + 16.0f)) {
        const float alpha = fexp2((m_r - mnew) * C2);
        l_r *= alpha;
#pragma unroll
        for (int d0 = 0; d0 < 4; ++d0) o[d0] *= alpha;
        m_r = mnew;
      }

#pragma unroll
      for (int r = 0; r < 16; ++r) {
        s0[r] = fexp2((s0[r] - m_r) * C2);
        s1[r] = fexp2((s1[r] - m_r) * C2);
      }
      float sm[8];
#pragma unroll
      for (int r = 0; r < 8; ++r) sm[r] = (s0[r] + s0[r + 8]) + (s1[r] + s1[r + 8]);
#pragma unroll
      for (int r = 0; r < 4; ++r) sm[r] += sm[r + 4];
      float ls = (sm[0] + sm[1]) + (sm[2] + sm[3]);
      ls += __shfl_xor(ls, 32);
      l_r += ls;

      const char* vsb = reinterpret_cast<const char*>(Vs[cur]);
#pragma unroll
      for (int ks = 0; ks < 4; ++ks) {
        float pj[8];
#pragma unroll
        for (int j = 0; j < 8; ++j)
          pj[j] = (ks >> 1) ? s1[(ks & 1) * 8 + j] : s0[(ks & 1) * 8 + j];
        unsigned cA = cvtpk_bf16(pj[0], pj[1]);
        unsigned cB = cvtpk_bf16(pj[2], pj[3]);
        unsigned cC = cvtpk_bf16(pj[4], pj[5]);
        unsigned cD = cvtpk_bf16(pj[6], pj[7]);
        asm volatile("v_permlane32_swap_b32 %0, %1" : "+v"(cA), "+v"(cC));
        asm volatile("v_permlane32_swap_b32 %0, %1" : "+v"(cB), "+v"(cD));
        union { unsigned u[4]; bf16x8 v; } pa;
        pa.u[0] = cA; pa.u[1] = cB; pa.u[2] = cC; pa.u[3] = cD;
        __builtin_amdgcn_s_setprio(1);
#pragma unroll
        for (int d0 = 0; d0 < 4; ++d0) {
          const int byt = (d0 * 32 + l31) * 128 + ((ks * 32 + hi * 16) ^ ((l31 & 7) << 4));
          bf16x8 av = *reinterpret_cast<const bf16x8*>(vsb + byt);
          o[d0] = mfma32(av, pa.v, o[d0]);
        }
        __builtin_amdgcn_s_setprio(0);
      }
    }

    if (more) { VM0(); }
    BARR();
  }

  const size_t obase = (size_t)(bh >> 4) * TSEQ * DM + (size_t)(bh & 15) * DH;
  const float inv = 1.0f / l_r;
  ushort_t* cp = ctx + obase + (size_t)q * DM + hi * 4;
#pragma unroll
  for (int d0 = 0; d0 < 4; ++d0) {
#pragma unroll
    for (int g = 0; g < 4; ++g) {
      ushort4 u;
      u.x = f2bf(o[d0][4 * g + 0] * inv);
      u.y = f2bf(o[d0][4 * g + 1] * inv);
      u.z = f2bf(o[d0][4 * g + 2] * inv);
      u.w = f2bf(o[d0][4 * g + 3] * inv);
      *reinterpret_cast<ushort4*>(cp + d0 * 32 + 8 * g) = u;
    }
  }
}

extern "C" void kernel_launch(void* const* d_in, const int* in_sizes, int n_in,
                              void* d_out, int out_size, void* d_ws, size_t ws_size,
                              hipStream_t stream) {
  const float* x  = (const float*)d_in[0];
  const float* Wq = (const float*)d_in[1];
  const float* bq = (const float*)d_in[2];
  const float* Wk = (const float*)d_in[3];
  const float* bk = (const float*)d_in[4];
  const float* Wv = (const float*)d_in[5];
  const float* bv = (const float*)d_in[6];
  const float* Wo = (const float*)d_in[7];
  const float* bo = (const float*)d_in[8];
  float* out = (float*)d_out;

  char* ws = (char*)d_ws;
  ushort_t* xb  = (ushort_t*)ws;  ws += (size_t)BT * DM * 2;      // x bf16; reused as ctx
  ushort_t* Wqb = (ushort_t*)ws;  ws += (size_t)DM * DM * 2;
  ushort_t* Wkb = (ushort_t*)ws;  ws += (size_t)DM * DM * 2;
  ushort_t* Wvb = (ushort_t*)ws;  ws += (size_t)DM * DM * 2;
  ushort_t* Wob = (ushort_t*)ws;  ws += (size_t)DM * DM * 2;
  ushort_t* Qb  = (ushort_t*)ws;  ws += (size_t)BT * DM * 2;
  ushort_t* Kb  = (ushort_t*)ws;  ws += (size_t)BT * DM * 2;
  ushort_t* Vtb = (ushort_t*)ws;  ws += (size_t)BT * DM * 2;
  ushort_t* ctxb = xb;   // alias: x dead after QKV GEMM

  // fused conversion: 6M float4 quads total (x 2M + 4 weights x 1M)
  cvt_all_kernel<<<6 * (1 << 20) / 256, 256, 0, stream>>>(
      x, Wq, Wk, Wv, Wo, xb, Wqb, Wkb, Wvb, Wob);

  gemm_qkv_fused<<<dim3(16, 32), 512, 0, stream>>>(
      xb, Wqb, Wkb, Wvb, bq, bk, bv, Qb, Kb, Vtb);

  attn_kernel<<<dim3(TSEQ / 128, 32), 256, 0, stream>>>(Qb, Kb, Vtb, ctxb);

  gemm_proj_kernel<<<dim3(16, 32), 256, 0, stream>>>(ctxb, Wob, bo, out);
}

// Round 17
// 247.212 us; speedup vs baseline: 1.1784x; 1.0974x over previous
//
#include <hip/hip_runtime.h>
#include <hip/hip_bf16.h>
#include <math.h>

typedef unsigned short ushort_t;
typedef short bf16x8 __attribute__((ext_vector_type(8)));
typedef float f32x4 __attribute__((ext_vector_type(4)));
typedef float f32x16 __attribute__((ext_vector_type(16)));

#define NH 16
#define DH 128
#define DM 2048
#define TSEQ 2048
#define BT 4096   // B*T

__device__ __forceinline__ void async16(const void* g, void* l) {
  __builtin_amdgcn_global_load_lds(
      (const __attribute__((address_space(1))) void*)g,
      (__attribute__((address_space(3))) void*)l, 16, 0, 0);
}

__device__ __forceinline__ f32x4 mfma16(bf16x8 a, bf16x8 b, f32x4 c) {
  return __builtin_amdgcn_mfma_f32_16x16x32_bf16(a, b, c, 0, 0, 0);
}
__device__ __forceinline__ f32x16 mfma32(bf16x8 a, bf16x8 b, f32x16 c) {
  return __builtin_amdgcn_mfma_f32_32x32x16_bf16(a, b, c, 0, 0, 0);
}

__device__ __forceinline__ ushort_t f2bf(float f) {
  __hip_bfloat16 h = __float2bfloat16(f);
  return *reinterpret_cast<ushort_t*>(&h);
}
__device__ __forceinline__ unsigned cvtpk_bf16(float lo, float hi_) {
  unsigned r;
  asm("v_cvt_pk_bf16_f32 %0, %1, %2" : "=v"(r) : "v"(lo), "v"(hi_));
  return r;
}
__device__ __forceinline__ float fexp2(float x) {
  float r; asm("v_exp_f32 %0, %1" : "=v"(r) : "v"(x)); return r;
}

#define VM0()  asm volatile("s_waitcnt vmcnt(0)" ::: "memory")
#define BARR() { asm volatile("" ::: "memory"); __builtin_amdgcn_s_barrier(); \
                 asm volatile("" ::: "memory"); }

// ---------------- fused fp32 -> bf16 conversion (x + 4 weights, one launch) ----------------
__global__ void cvt_all_kernel(const float* __restrict__ x,
                               const float* __restrict__ Wq, const float* __restrict__ Wk,
                               const float* __restrict__ Wv, const float* __restrict__ Wo,
                               ushort_t* __restrict__ xb,
                               ushort_t* __restrict__ Wqb, ushort_t* __restrict__ Wkb,
                               ushort_t* __restrict__ Wvb, ushort_t* __restrict__ Wob)
{
  const int i = blockIdx.x * blockDim.x + threadIdx.x;   // 0 .. 6M-1 float4 quads
  const float* src; ushort_t* dst; int off;
  if (i < (1 << 21)) {                    // x: 8M elems = 2M quads
    src = x; dst = xb; off = i;
  } else {
    const int j = i - (1 << 21);          // weights: 4M elems = 1M quads each
    const int w = j >> 20;
    off = j & ((1 << 20) - 1);
    src = (w == 0) ? Wq : (w == 1) ? Wk : (w == 2) ? Wv : Wo;
    dst = (w == 0) ? Wqb : (w == 1) ? Wkb : (w == 2) ? Wvb : Wob;
  }
  const float4 v = reinterpret_cast<const float4*>(src)[off];
  ushort4 u;
  u.x = f2bf(v.x); u.y = f2bf(v.y); u.z = f2bf(v.z); u.w = f2bf(v.w);
  reinterpret_cast<ushort4*>(dst)[off] = u;
}

// ---------------- fused QKV GEMM, single-barrier T3-minimum schedule ----------------
__device__ __forceinline__ void stage_half_g(const ushort_t* __restrict__ src,
                                             int row0, int k0,
                                             ushort_t* dst, int tid) {
#pragma unroll
  for (int i = 0; i < 2; ++i) {
    const int idx = i * 512 + tid;
    const int r = idx >> 3, ch = idx & 7;
    const int c = (ch ^ (r & 7)) * 8;           // pre-swizzled source chunk
    async16(src + (size_t)(row0 + r) * DM + k0 + c, dst + idx * 8);
  }
}

__global__ __launch_bounds__(512, 2)
void gemm_qkv_fused(const ushort_t* __restrict__ A,
                    const ushort_t* __restrict__ W_0, const ushort_t* __restrict__ W_1,
                    const ushort_t* __restrict__ W_2,
                    const float* __restrict__ b_0, const float* __restrict__ b_1,
                    const float* __restrict__ b_2,
                    ushort_t* __restrict__ outQ, ushort_t* __restrict__ outK,
                    ushort_t* __restrict__ outVt)
{
  constexpr int NK = DM / 64;
  __shared__ __attribute__((aligned(16))) ushort_t As[2][128 * 64];
  __shared__ __attribute__((aligned(16))) ushort_t Bs[2][3][128 * 64];

  const int n0 = blockIdx.x * 128;
  const int m0 = blockIdx.y * 128;
  const int tid = threadIdx.x;
  const int w = tid >> 6, l = tid & 63;
  const int wr = w >> 2, wc = w & 3;
  const int l15 = l & 15, l4 = l >> 4;

  f32x4 acc[3][4][2] = {};   // [z][mf][nf]
  bf16x8 afr[4][2], bfr[2][2];

  stage_half_g(A,   m0, 0, As[0],    tid);
  stage_half_g(W_0, n0, 0, Bs[0][0], tid);
  stage_half_g(W_1, n0, 0, Bs[0][1], tid);
  stage_half_g(W_2, n0, 0, Bs[0][2], tid);
  VM0();
  BARR();

  for (int kt = 0; kt < NK; ++kt) {
    const int cur = kt & 1;
    const bool more = (kt + 1 < NK);
    if (more) {
      const int k1 = (kt + 1) * 64;
      stage_half_g(A,   m0, k1, As[cur ^ 1],    tid);
      stage_half_g(W_0, n0, k1, Bs[cur ^ 1][0], tid);
      stage_half_g(W_1, n0, k1, Bs[cur ^ 1][1], tid);
      stage_half_g(W_2, n0, k1, Bs[cur ^ 1][2], tid);
    }

    {
      const char* p_ = reinterpret_cast<const char*>(As[cur]);
#pragma unroll
      for (int mf = 0; mf < 4; ++mf) {
        const int row_ = wr * 64 + mf * 16 + l15;
#pragma unroll
        for (int ks = 0; ks < 2; ++ks)
          afr[mf][ks] = *reinterpret_cast<const bf16x8*>(
              p_ + row_ * 128 + ((l4 * 16 + ks * 64) ^ ((row_ & 7) << 4)));
      }
    }
#pragma unroll
    for (int z = 0; z < 3; ++z) {
      const char* p_ = reinterpret_cast<const char*>(Bs[cur][z]);
#pragma unroll
      for (int nf = 0; nf < 2; ++nf) {
        const int row_ = wc * 32 + nf * 16 + l15;
#pragma unroll
        for (int ks = 0; ks < 2; ++ks)
          bfr[nf][ks] = *reinterpret_cast<const bf16x8*>(
              p_ + row_ * 128 + ((l4 * 16 + ks * 64) ^ ((row_ & 7) << 4)));
      }
      __builtin_amdgcn_s_setprio(1);
#pragma unroll
      for (int mf = 0; mf < 4; ++mf)
#pragma unroll
        for (int nf = 0; nf < 2; ++nf)
#pragma unroll
          for (int ks = 0; ks < 2; ++ks)
            acc[z][mf][nf] = mfma16(afr[mf][ks], bfr[nf][ks], acc[z][mf][nf]);
      __builtin_amdgcn_s_setprio(0);
    }

    if (more) { VM0(); }
    BARR();
  }

#pragma unroll
  for (int z = 0; z < 3; ++z) {
    const float* bias = (z == 0) ? b_0 : (z == 1) ? b_1 : b_2;
#pragma unroll
    for (int nf = 0; nf < 2; ++nf) {
      const int n = n0 + wc * 32 + nf * 16 + l15;
      const float bv = bias[n];
      const int hh = n >> 7, d = n & 127;
#pragma unroll
      for (int mf = 0; mf < 4; ++mf) {
#pragma unroll
        for (int r = 0; r < 4; ++r) {
          const int m = m0 + wr * 64 + mf * 16 + l4 * 4 + r;
          const float v = acc[z][mf][nf][r] + bv;
          const int b = m >> 11, t = m & 2047;
          const ushort_t val = f2bf(v);
          if (z == 2) {
            outVt[((size_t)(b * NH + hh) * DH + d) * TSEQ + t] = val;   // V transposed
          } else {
            ushort_t* dst = (z == 0) ? outQ : outK;
            dst[((size_t)(b * NH + hh) * TSEQ + t) * DH + d] = val;
          }
        }
      }
    }
  }
}

// ---------------- out-projection GEMM, single-barrier schedule ----------------
__device__ __forceinline__ void stage_ab(const ushort_t* __restrict__ A,
                                         const ushort_t* __restrict__ Wp,
                                         int m0, int n0, int k0,
                                         ushort_t* AsB, ushort_t* BsB,
                                         int w, int l)
{
#pragma unroll
  for (int i = 0; i < 4; ++i) {
    const int rb = (i * 4 + w) * 8;
    const int r = rb + (l >> 3);
    const int c = ((l & 7) * 8) ^ ((r & 7) * 8);   // pre-swizzled source col
    async16(A  + (size_t)(m0 + r) * DM + k0 + c, AsB + rb * 64);
    async16(Wp + (size_t)(n0 + r) * DM + k0 + c, BsB + rb * 64);
  }
}

__global__ __launch_bounds__(256)
void gemm_proj_kernel(const ushort_t* __restrict__ A, const ushort_t* __restrict__ W_0,
                      const float* __restrict__ b_0, float* __restrict__ outF)
{
  constexpr int NK = DM / 64;
  __shared__ __attribute__((aligned(16))) ushort_t As[2][128 * 64];
  __shared__ __attribute__((aligned(16))) ushort_t Bs[2][128 * 64];

  const int n0 = blockIdx.x * 128;
  const int m0 = blockIdx.y * 128;
  const int tid = threadIdx.x;
  const int w = tid >> 6, l = tid & 63;
  const int wm = w >> 1, wn = w & 1;
  const int l15 = l & 15, l4 = l >> 4;

  f32x4 zero = {0.f, 0.f, 0.f, 0.f};
  f32x4 acc[4][4];
#pragma unroll
  for (int i = 0; i < 4; ++i)
#pragma unroll
    for (int j = 0; j < 4; ++j) acc[i][j] = zero;

  stage_ab(A, W_0, m0, n0, 0, As[0], Bs[0], w, l);
  VM0();
  BARR();

  for (int kt = 0; kt < NK; ++kt) {
    const int cur = kt & 1;
    const bool more = (kt + 1 < NK);
    if (more)
      stage_ab(A, W_0, m0, n0, (kt + 1) * 64, As[cur ^ 1], Bs[cur ^ 1], w, l);

#pragma unroll
    for (int ks = 0; ks < 2; ++ks) {
      bf16x8 af[4], bfr[4];
#pragma unroll
      for (int mf = 0; mf < 4; ++mf) {
        const int row = wm * 64 + mf * 16 + l15;
        const int byte_ = row * 128 + ((l4 * 16 + ks * 64) ^ ((row & 7) << 4));
        af[mf] = *reinterpret_cast<const bf16x8*>(reinterpret_cast<const char*>(As[cur]) + byte_);
      }
#pragma unroll
      for (int nf = 0; nf < 4; ++nf) {
        const int row = wn * 64 + nf * 16 + l15;
        const int byte_ = row * 128 + ((l4 * 16 + ks * 64) ^ ((row & 7) << 4));
        bfr[nf] = *reinterpret_cast<const bf16x8*>(reinterpret_cast<const char*>(Bs[cur]) + byte_);
      }
      __builtin_amdgcn_s_setprio(1);
#pragma unroll
      for (int mf = 0; mf < 4; ++mf)
#pragma unroll
        for (int nf = 0; nf < 4; ++nf)
          acc[mf][nf] = mfma16(af[mf], bfr[nf], acc[mf][nf]);
      __builtin_amdgcn_s_setprio(0);
    }

    if (more) { VM0(); }
    BARR();
  }

#pragma unroll
  for (int nf = 0; nf < 4; ++nf) {
    const int n = n0 + wn * 64 + nf * 16 + l15;
    const float bv = b_0[n];
#pragma unroll
    for (int mf = 0; mf < 4; ++mf) {
#pragma unroll
      for (int r = 0; r < 4; ++r) {
        const int m = m0 + wm * 64 + mf * 16 + l4 * 4 + r;
        outF[(size_t)m * DM + n] = acc[mf][nf][r] + bv;
      }
    }
  }
}

// ---------------- causal flash attention, MERGED complementary pairs ----------------
// One 512-thread block = waves 0-3 on heavy tile qtA (128 rows) + waves 4-7 on
// light tile qtB = 15-qtA of the SAME bh. The light tile's KV range is a prefix
// of the heavy's, so ONE shared KV staging stream serves both: per-CU staging
// drops from 36 iters x 64KB (two independent blocks) to <=32 iters x 32KB, and
// each bh's KV is read by 8 blocks instead of 16 (FETCH halves). Light waves
// drop out of compute via the existing kv0<=wq0+31 guard but keep staging and
// hitting barriers. Grid 256 = 1 block/CU; all 8 blocks of a bh on one XCD
// (4 bh x 1MB KV = 4MB = one L2). Compute loop body identical to R16 (proven).
__device__ __forceinline__ void stage_kv(const ushort_t* __restrict__ Kg,
                                         const ushort_t* __restrict__ Vt,
                                         size_t kbase, size_t vbase, int kv0,
                                         ushort_t* KsB, ushort_t* VsB, int tid)
{
#pragma unroll
  for (int i = 0; i < 2; ++i) {           // K tile [64 kv][128 d], 16KB, 512 thr
    const int idx = i * 512 + tid;
    const int r = idx >> 4, ch = idx & 15;
    const int c = (ch ^ (r & 7)) * 8;
    async16(Kg + kbase + (size_t)(kv0 + r) * DH + c, KsB + idx * 8);
  }
#pragma unroll
  for (int i = 0; i < 2; ++i) {           // V^T tile [128 d][64 kv], 16KB, 512 thr
    const int idx = i * 512 + tid;
    const int d = idx >> 3, ch = idx & 7;
    const int c = (ch ^ (d & 7)) * 8;
    async16(Vt + vbase + (size_t)d * TSEQ + kv0 + c, VsB + idx * 8);
  }
}

__global__ __launch_bounds__(512)
void attn_kernel(const ushort_t* __restrict__ Q, const ushort_t* __restrict__ Kg,
                 const ushort_t* __restrict__ Vt, ushort_t* __restrict__ ctx)
{
  __shared__ __attribute__((aligned(16))) ushort_t Ks[2][64 * 128];
  __shared__ __attribute__((aligned(16))) ushort_t Vs[2][128 * 64];

  // fid <-> (x=fid&7, y=(fid>>3)&3, z=fid>>5), 8x4x8 = 256 bijective.
  // bh = 4x+y (all 8 blocks of a bh share XCD x, assuming fid%8 round-robin);
  // qtA = 15-z (heavy, dispatched first), qtB = z.
  const int fid = (int)blockIdx.x + 8 * (int)blockIdx.y;
  const int bh  = 4 * (fid & 7) + ((fid >> 3) & 3);
  const int qtA = 15 - (fid >> 5);
  const int qtB = 15 - qtA;

  const int tid = threadIdx.x, w = tid >> 6, l = tid & 63;
  const int l31 = l & 31, hi = l >> 5;
  const size_t kbase = (size_t)bh * TSEQ * DH;
  const size_t vbase = (size_t)bh * DH * TSEQ;
  const int qt_w = (w < 4) ? qtA : qtB;          // this wave's q-tile
  const int wq0 = qt_w * 128 + (w & 3) * 32;     // this wave's first q row
  const int NT = qtA * 2 + 2;                    // kv tiles for the heavy tile
  const int q = wq0 + l31;
  const float C2 = 0.12753842f;           // log2(e)/sqrt(128)
  const float NEG = -3.0e38f;

  bf16x8 aq[8];
  {
    const ushort_t* qp = Q + kbase + (size_t)q * DH + hi * 8;
#pragma unroll
    for (int st = 0; st < 8; ++st)
      aq[st] = *reinterpret_cast<const bf16x8*>(qp + st * 16);
  }

  f32x16 o[4] = {};
  float m_r = NEG, l_r = 0.f;

  stage_kv(Kg, Vt, kbase, vbase, 0, Ks[0], Vs[0], tid);
  VM0();
  BARR();

  for (int kt = 0; kt < NT; ++kt) {
    const int kv0 = kt * 64, cur = kt & 1;
    const bool more = (kt + 1 < NT);
    if (more)
      stage_kv(Kg, Vt, kbase, vbase, kv0 + 64, Ks[cur ^ 1], Vs[cur ^ 1], tid);

    if (kv0 <= wq0 + 31) {       // wave participates (light waves drop out early)
      const char* ksb = reinterpret_cast<const char*>(Ks[cur]);
      f32x16 s0 = {}, s1 = {};
      __builtin_amdgcn_s_setprio(1);
#pragma unroll
      for (int st = 0; st < 8; ++st) {
        const int byt = l31 * 256 + ((hi * 16 + st * 32) ^ ((l31 & 7) << 4));
        bf16x8 ak0 = *reinterpret_cast<const bf16x8*>(ksb + byt);
        bf16x8 ak1 = *reinterpret_cast<const bf16x8*>(ksb + byt + 8192);
        s0 = mfma32(ak0, aq[st], s0);
        s1 = mfma32(ak1, aq[st], s1);
      }
      __builtin_amdgcn_s_setprio(0);

      if (kv0 + 63 > wq0) {
#pragma unroll
        for (int r = 0; r < 16; ++r) {
          const int kvl = kv0 + (r & 3) + 8 * (r >> 2) + 4 * hi;
          if (kvl > q)      s0[r] = NEG;
          if (kvl + 32 > q) s1[r] = NEG;
        }
      }

      float t8[8];
#pragma unroll
      for (int r = 0; r < 8; ++r)
        t8[r] = fmaxf(fmaxf(s0[r], s0[r + 8]), fmaxf(s1[r], s1[r + 8]));
#pragma unroll
      for (int r = 0; r < 4; ++r) t8[r] = fmaxf(t8[r], t8[r + 4]);
      float mt = fmaxf(fmaxf(t8[0], t8[1]), fmaxf(t8[2], t8[3]));
      mt = fmaxf(mt, __shfl_xor(mt, 32));

      const float mnew = fmaxf(m_r, mt);
      if (!__all(mt <= m_r + 16.0f)) {
        const float alpha = fexp2((m_r - mnew) * C2);
        l_r *= alpha;
#pragma unroll
        for (int d0 = 0; d0 < 4; ++d0) o[d0] *= alpha;
        m_r = mnew;
      }

#pragma unroll
      for (int r = 0; r < 16; ++r) {
        s0[r] = fexp2((s0[r] - m_r) * C2);
        s1[r] = fexp2((s1[r] - m_r) * C2);
      }
      float sm[8];
#pragma unroll
      for (int r = 0; r < 8; ++r) sm[r] = (s0[r] + s0[r + 8]) + (s1[r] + s1[r + 8]);
#pragma unroll
      for (int r = 0; r < 4; ++r) sm[r] += sm[r + 4];
      float ls = (sm[0] + sm[1]) + (sm[2] + sm[3]);
      ls += __shfl_xor(ls, 32);
      l_r += ls;

      const char* vsb = reinterpret_cast<const char*>(Vs[cur]);
#pragma unroll
      for (int ks = 0; ks < 4; ++ks) {
        float pj[8];
#pragma unroll
        for (int j = 0; j < 8; ++j)
          pj[j] = (ks >> 1) ? s1[(ks & 1) * 8 + j] : s0[(ks & 1) * 8 + j];
        unsigned cA = cvtpk_bf16(pj[0], pj[1]);
        unsigned cB = cvtpk_bf16(pj[2], pj[3]);
        unsigned cC = cvtpk_bf16(pj[4], pj[5]);
        unsigned cD = cvtpk_bf16(pj[6], pj[7]);
        asm volatile("v_permlane32_swap_b32 %0, %1" : "+v"(cA), "+v"(cC));
        asm volatile("v_permlane32_swap_b32 %0, %1" : "+v"(cB), "+v"(cD));
        union { unsigned u[4]; bf16x8 v; } pa;
        pa.u[0] = cA; pa.u[1] = cB; pa.u[2] = cC; pa.u[3] = cD;
        __builtin_amdgcn_s_setprio(1);
#pragma unroll
        for (int d0 = 0; d0 < 4; ++d0) {
          const int byt = (d0 * 32 + l31) * 128 + ((ks * 32 + hi * 16) ^ ((l31 & 7) << 4));
          bf16x8 av = *reinterpret_cast<const bf16x8*>(vsb + byt);
          o[d0] = mfma32(av, pa.v, o[d0]);
        }
        __builtin_amdgcn_s_setprio(0);
      }
    }

    if (more) { VM0(); }
    BARR();
  }

  const size_t obase = (size_t)(bh >> 4) * TSEQ * DM + (size_t)(bh & 15) * DH;
  const float inv = 1.0f / l_r;
  ushort_t* cp = ctx + obase + (size_t)q * DM + hi * 4;
#pragma unroll
  for (int d0 = 0; d0 < 4; ++d0) {
#pragma unroll
    for (int g = 0; g < 4; ++g) {
      ushort4 u;
      u.x = f2bf(o[d0][4 * g + 0] * inv);
      u.y = f2bf(o[d0][4 * g + 1] * inv);
      u.z = f2bf(o[d0][4 * g + 2] * inv);
      u.w = f2bf(o[d0][4 * g + 3] * inv);
      *reinterpret_cast<ushort4*>(cp + d0 * 32 + 8 * g) = u;
    }
  }
}

extern "C" void kernel_launch(void* const* d_in, const int* in_sizes, int n_in,
                              void* d_out, int out_size, void* d_ws, size_t ws_size,
                              hipStream_t stream) {
  const float* x  = (const float*)d_in[0];
  const float* Wq = (const float*)d_in[1];
  const float* bq = (const float*)d_in[2];
  const float* Wk = (const float*)d_in[3];
  const float* bk = (const float*)d_in[4];
  const float* Wv = (const float*)d_in[5];
  const float* bv = (const float*)d_in[6];
  const float* Wo = (const float*)d_in[7];
  const float* bo = (const float*)d_in[8];
  float* out = (float*)d_out;

  char* ws = (char*)d_ws;
  ushort_t* xb  = (ushort_t*)ws;  ws += (size_t)BT * DM * 2;      // x bf16; reused as ctx
  ushort_t* Wqb = (ushort_t*)ws;  ws += (size_t)DM * DM * 2;
  ushort_t* Wkb = (ushort_t*)ws;  ws += (size_t)DM * DM * 2;
  ushort_t* Wvb = (ushort_t*)ws;  ws += (size_t)DM * DM * 2;
  ushort_t* Wob = (ushort_t*)ws;  ws += (size_t)DM * DM * 2;
  ushort_t* Qb  = (ushort_t*)ws;  ws += (size_t)BT * DM * 2;
  ushort_t* Kb  = (ushort_t*)ws;  ws += (size_t)BT * DM * 2;
  ushort_t* Vtb = (ushort_t*)ws;  ws += (size_t)BT * DM * 2;
  ushort_t* ctxb = xb;   // alias: x dead after QKV GEMM

  // fused conversion: 6M float4 quads total (x 2M + 4 weights x 1M)
  cvt_all_kernel<<<6 * (1 << 20) / 256, 256, 0, stream>>>(
      x, Wq, Wk, Wv, Wo, xb, Wqb, Wkb, Wvb, Wob);

  gemm_qkv_fused<<<dim3(16, 32), 512, 0, stream>>>(
      xb, Wqb, Wkb, Wvb, bq, bk, bv, Qb, Kb, Vtb);

  attn_kernel<<<dim3(8, 32), 512, 0, stream>>>(Qb, Kb, Vtb, ctxb);

  gemm_proj_kernel<<<dim3(16, 32), 256, 0, stream>>>(ctxb, Wob, bo, out);
}